// Round 4
// baseline (689.375 us; speedup 1.0000x reference)
//
#include <hip/hip_runtime.h>
#include <hip/hip_bf16.h>

// Problem constants: features [B=32, D=1024, M=512] fp32.
#define B_ 32
#define D_ 1024
#define M_ 512
#define OUTROW 524800  // D*(D+1)/2
#define ALPHA_ 0.4f
#define EPS_ 1e-5f

typedef __bf16 bf16x8 __attribute__((ext_vector_type(8)));
typedef float f32x4 __attribute__((ext_vector_type(4)));

// ---------------------------------------------------------------------------
// Kernel A: cast features fp32->bf16 + diag[b,d] = sum_m f^2 / (2M) (fp32).
// One wave per row (512 elems), 4 rows per 256-thread block.
// Also zeroes rowsum/totals/done (folded memset: saves a dispatch).
// ---------------------------------------------------------------------------
__global__ __launch_bounds__(256) void prep_kernel(
    const float* __restrict__ feat, __bf16* __restrict__ featbf,
    float* __restrict__ diag, float* __restrict__ rowsum,
    float* __restrict__ totals, int* __restrict__ done)
{
    // folded accumulator zeroing: 128 blocks x 256 threads = 32768 = B*D
    if (blockIdx.x < 128) {
        rowsum[blockIdx.x * 256 + threadIdx.x] = 0.0f;
        if (blockIdx.x == 0 && threadIdx.x < B_) {
            totals[threadIdx.x] = 0.0f;
            done[threadIdx.x] = 0;
        }
    }

    const int w = threadIdx.x >> 6, l = threadIdx.x & 63;
    const int row = blockIdx.x * 4 + w;          // 0 .. 32767
    const float4* fp = (const float4*)(feat + (size_t)row * M_);
    float4 v0 = fp[l * 2];
    float4 v1 = fp[l * 2 + 1];
    bf16x8 h;
    h[0] = (__bf16)v0.x; h[1] = (__bf16)v0.y; h[2] = (__bf16)v0.z; h[3] = (__bf16)v0.w;
    h[4] = (__bf16)v1.x; h[5] = (__bf16)v1.y; h[6] = (__bf16)v1.z; h[7] = (__bf16)v1.w;
    *(bf16x8*)(featbf + (size_t)row * M_ + l * 8) = h;
    float s = v0.x*v0.x + v0.y*v0.y + v0.z*v0.z + v0.w*v0.w
            + v1.x*v1.x + v1.y*v1.y + v1.z*v1.z + v1.w*v1.w;
    #pragma unroll
    for (int off = 32; off; off >>= 1) s += __shfl_down(s, off);
    if (l == 0) diag[row] = s * (1.0f / (2.0f * M_));
}

// ---------------------------------------------------------------------------
// Kernel B: upper-triangular-tile Gram GEMM (bf16 MFMA 16x16x32), fused
// dcov -> pow epilogue, XCD-batch-swizzled, AND fused double-centering:
// the 36 blocks of a batch form a cohort (contiguous blockIdx range of 288
// per 8-batch group); after the epilogue each block release-arrives on
// done[b]; when the cohort is complete the 36 blocks center out[b] (2.1 MB,
// still dirty in their shared XCD L2) cooperatively. Centering of group g
// overlaps the k-loops of group g+1 (which are latency-bound, <20% busy).
// Deadlock-safe: cohort spans 288 consecutive blockIdx; guaranteed residency
// 3 blocks/CU x 256 CU = 768 >= 288, dispatch in blockIdx order.
// ---------------------------------------------------------------------------
__global__ __launch_bounds__(256, 3) void gram_kernel(
    const __bf16* __restrict__ feat, const float* __restrict__ diag,
    float* __restrict__ out, float* __restrict__ rowsum,
    float* __restrict__ totals, int* __restrict__ done)
{
    // [stage%3][slot] ; slot = row*4 + swizzled-chunk, 16B per slot
    __shared__ __bf16 As[3][512 * 8];
    __shared__ __bf16 Bs[3][512 * 8];

    const int t = threadIdx.x;
    const int w = t >> 6, l = t & 63;
    const int quad = l >> 4, l15 = l & 15;

    // XCD-aware decode: linear id -> (xcd, slot); each XCD owns batches
    // {xcd, xcd+8, xcd+16, xcd+24} processed sequentially -> per-XCD L2 reuse.
    const int L = blockIdx.x;
    const int xcd = L & 7;
    const int slot = L >> 3;                 // 0..143
    const int b = xcd + 8 * (slot / 36);
    const int rank = slot % 36;              // cohort rank 0..35
    int u = rank, ti = 0;
    while (u >= 8 - ti) { u -= 8 - ti; ti++; }
    const int tj = ti + u;
    const bool diagTile = (ti == tj);

    const __bf16* Ab = feat + (size_t)b * (D_ * M_) + (size_t)ti * 128 * M_;
    const __bf16* Bb = feat + (size_t)b * (D_ * M_) + (size_t)tj * 128 * M_;

    const int wm = w >> 1, wn = w & 1;

    // Preload diag fragments now: global-load latency hides under the K-loop.
    const int gi0 = ti * 128 + wm * 64;
    const int gj0 = tj * 128 + wn * 64;
    const float* diagB = diag + b * D_;
    float di[4][4], dj[4];
    #pragma unroll
    for (int mi = 0; mi < 4; ++mi)
        #pragma unroll
        for (int r = 0; r < 4; ++r)
            di[mi][r] = diagB[gi0 + mi * 16 + quad * 4 + r];
    #pragma unroll
    for (int nj = 0; nj < 4; ++nj)
        dj[nj] = diagB[gj0 + nj * 16 + l15];

    f32x4 acc[4][4] = {};

    // stage s: load A/B rows [0,128) cols [s*32, s*32+32) into buffer sb.
    // LDS dest is linear per wave (global_load_lds requirement); the bank
    // swizzle is applied on the per-lane GLOBAL source address (m173 pattern).
    auto stage = [&](int s, int sb) {
        const int koff = s * 32;
        #pragma unroll
        for (int it = 0; it < 2; ++it) {
            const int idx = it * 256 + t;          // slot 0..511
            const int row = idx >> 2;              // 0..127
            const int cg = (idx & 3) ^ ((row >> 1) & 3);  // swizzled chunk-of-8
            const __bf16* ga = Ab + row * M_ + koff + cg * 8;
            const __bf16* gb = Bb + row * M_ + koff + cg * 8;
            __builtin_amdgcn_global_load_lds(
                (const __attribute__((address_space(1))) void*)ga,
                (__attribute__((address_space(3))) void*)(&As[sb][(it * 256 + w * 64) * 8]),
                16, 0, 0);
            __builtin_amdgcn_global_load_lds(
                (const __attribute__((address_space(1))) void*)gb,
                (__attribute__((address_space(3))) void*)(&Bs[sb][(it * 256 + w * 64) * 8]),
                16, 0, 0);
        }
    };

    stage(0, 0);          // 4 loads/thread in flight
    stage(1, 1);          // 8 in flight
    int rb = 0, sn = 2;   // read buffer, next stage buffer
    for (int k0 = 0; k0 < 16; ++k0) {
        // Counted wait: own buffer-k0 loads (oldest 4) complete; the 4
        // prefetch loads for k0+1 stay in flight across the barrier.
        if (k0 < 15) asm volatile("s_waitcnt vmcnt(4)" ::: "memory");
        else         asm volatile("s_waitcnt vmcnt(0)" ::: "memory");
        __builtin_amdgcn_s_barrier();
        __builtin_amdgcn_sched_barrier(0);   // pin: nothing moves above barrier
        if (k0 + 2 < 16) stage(k0 + 2, sn);  // depth-2 prefetch

        bf16x8 af[4], bfr[4];
        #pragma unroll
        for (int mi = 0; mi < 4; ++mi) {
            const int row = wm * 64 + mi * 16 + l15;
            af[mi] = *(const bf16x8*)(&As[rb][(row * 4 + (quad ^ ((row >> 1) & 3))) * 8]);
        }
        #pragma unroll
        for (int nj = 0; nj < 4; ++nj) {
            const int row = wn * 64 + nj * 16 + l15;
            bfr[nj] = *(const bf16x8*)(&Bs[rb][(row * 4 + (quad ^ ((row >> 1) & 3))) * 8]);
        }
        __builtin_amdgcn_s_setprio(1);
        #pragma unroll
        for (int mi = 0; mi < 4; ++mi)
            #pragma unroll
            for (int nj = 0; nj < 4; ++nj)
                acc[mi][nj] = __builtin_amdgcn_mfma_f32_16x16x32_bf16(
                    af[mi], bfr[nj], acc[mi][nj], 0, 0, 0);
        __builtin_amdgcn_s_setprio(0);
        rb = (rb == 2) ? 0 : rb + 1;
        sn = (sn == 2) ? 0 : sn + 1;
    }

    // ---------------- epilogue ----------------
    float* outB = out + (size_t)b * OUTROW;
    float rs[4][4] = {};
    float cs[4] = {};
    float wt = 0.f;
    const float invK = 1.0f / 512.0f;  // dcov = di + dj - dot/512

    #pragma unroll
    for (int mi = 0; mi < 4; ++mi) {
        #pragma unroll
        for (int nj = 0; nj < 4; ++nj) {
            const f32x4 a = acc[mi][nj];
            const int j = gj0 + nj * 16 + l15;
            #pragma unroll
            for (int r = 0; r < 4; ++r) {
                const int i = gi0 + mi * 16 + quad * 4 + r;
                float d = di[mi][r] + dj[nj] - a[r] * invK;
                if (i == j) d = 0.0f;   // exact: ref has dcov(i,i) == 0
                d = fmaxf(d, 0.0f);
                const float p = __builtin_exp2f(ALPHA_ * __builtin_log2f(d + EPS_));
                rs[mi][r] += p;
                cs[nj] += p;
                wt += p;
                if (!diagTile || j >= i)
                    outB[(size_t)i * D_ - ((size_t)i * (i + 1)) / 2 + j] = p;
            }
        }
    }

    // row-sum contributions: reduce across l15 lanes
    #pragma unroll
    for (int mi = 0; mi < 4; ++mi) {
        #pragma unroll
        for (int r = 0; r < 4; ++r) {
            float v = rs[mi][r];
            v += __shfl_xor(v, 1); v += __shfl_xor(v, 2);
            v += __shfl_xor(v, 4); v += __shfl_xor(v, 8);
            if (l15 == 0)
                unsafeAtomicAdd(&rowsum[b * D_ + gi0 + mi * 16 + quad * 4 + r], v);
        }
    }
    // col-sum contributions map to rowsum[j] by symmetry (off-diag tiles only)
    if (!diagTile) {
        #pragma unroll
        for (int nj = 0; nj < 4; ++nj) {
            float v = cs[nj];
            v += __shfl_xor(v, 16); v += __shfl_xor(v, 32);
            if (quad == 0)
                unsafeAtomicAdd(&rowsum[b * D_ + gj0 + nj * 16 + l15], v);
        }
    }
    // batch total (off-diag tiles counted twice: tile + mirror)
    float v = wt;
    #pragma unroll
    for (int off = 32; off; off >>= 1) v += __shfl_down(v, off);
    if (l == 0) unsafeAtomicAdd(&totals[b], diagTile ? v : 2.0f * v);

    // ---------------- fused centering ----------------
    // Release-arrive: all this block's stores/atomics visible before the add.
    __threadfence();
    __syncthreads();
    if (t == 0) {
        __hip_atomic_fetch_add(&done[b], 1, __ATOMIC_RELEASE,
                               __HIP_MEMORY_SCOPE_AGENT);
        while (__hip_atomic_load(&done[b], __ATOMIC_ACQUIRE,
                                 __HIP_MEMORY_SCOPE_AGENT) < 36)
            __builtin_amdgcn_s_sleep(8);
    }
    __syncthreads();   // broadcast "cohort complete" to all threads

    // Cooperative centering of this batch: 36 blocks x 256 threads over the
    // 131200 float4 groups of the packed triangle (L2-resident RMW).
    {
        const int tot4 = OUTROW / 4;             // 131200
        const int chunk = 3645;                  // ceil(131200/36)
        const int g0 = rank * chunk;
        const int g1 = (g0 + chunk < tot4) ? g0 + chunk : tot4;
        const float invD = 1.0f / (float)D_;
        const float* rsB = rowsum + b * D_;
        const float tm = totals[b] * (1.0f / ((float)D_ * (float)D_));

        for (int g = g0 + t; g < g1; g += 256) {
            const int e = g * 4;
            // row from flat index (D=1024: (2D+1)^2 = 2049^2 = 4198401)
            const float disc = 4198401.0f - 8.0f * (float)e;
            int i = (int)((2049.0f - __builtin_sqrtf(disc)) * 0.5f);
            if (i > 1023) i = 1023;
            if (i < 0) i = 0;
            while (i * (2049 - i) / 2 > e) --i;
            while ((i + 1) * (2049 - (i + 1)) / 2 <= e) ++i;

            float4 vv = *(float4*)(outB + e);
            float r[4] = {vv.x, vv.y, vv.z, vv.w};
            int ii = i;
            int si = ii * (2049 - ii) / 2;            // start(ii)
            int sn2 = (ii + 1) * (2049 - ii - 1) / 2; // start(ii+1)
            #pragma unroll
            for (int q = 0; q < 4; ++q) {
                const int eq = e + q;
                while (eq >= sn2) {                   // row crossing (short rows)
                    ++ii; si = sn2;
                    sn2 = (ii + 1) * (2049 - ii - 1) / 2;
                }
                const int j = eq - si + ii;
                r[q] = r[q] - (rsB[ii] + rsB[j]) * invD + tm;
            }
            vv.x = r[0]; vv.y = r[1]; vv.z = r[2]; vv.w = r[3];
            *(float4*)(outB + e) = vv;
        }
    }
}

// ---------------------------------------------------------------------------
extern "C" void kernel_launch(void* const* d_in, const int* in_sizes, int n_in,
                              void* d_out, int out_size, void* d_ws, size_t ws_size,
                              hipStream_t stream) {
    const float* feat = (const float*)d_in[0];
    float* out = (float*)d_out;

    char* ws = (char*)d_ws;
    __bf16* featbf = (__bf16*)ws;                            // 33,554,432 B
    float* diag    = (float*)(ws + 33554432);                //    131,072 B
    float* rowsum  = (float*)(ws + 33554432 + 131072);       //    131,072 B
    float* totals  = (float*)(ws + 33554432 + 262144);       //        128 B
    int*   done    = (int*)  (ws + 33554432 + 262144 + 128); //        128 B

    // rowsum/totals/done zeroing folded into prep_kernel (stream-ordered
    // before gram)
    prep_kernel<<<dim3((B_ * D_) / 4), dim3(256), 0, stream>>>(feat, featbf, diag,
                                                               rowsum, totals, done);
    gram_kernel<<<dim3(36 * B_), dim3(256), 0, stream>>>(featbf, diag, out, rowsum,
                                                         totals, done);
}

// Round 5
// 211.452 us; speedup vs baseline: 3.2602x; 3.2602x over previous
//
#include <hip/hip_runtime.h>
#include <hip/hip_bf16.h>

// Problem constants: features [B=32, D=1024, M=512] fp32.
#define B_ 32
#define D_ 1024
#define M_ 512
#define OUTROW 524800  // D*(D+1)/2
#define ALPHA_ 0.4f
#define EPS_ 1e-5f

typedef __bf16 bf16x8 __attribute__((ext_vector_type(8)));
typedef float f32x4 __attribute__((ext_vector_type(4)));

// ---------------------------------------------------------------------------
// Kernel A: cast features fp32->bf16 + diag[b,d] = sum_m f^2 / (2M) (fp32).
// One wave per row (512 elems), 4 rows per 256-thread block.
// Also zeroes rowsum/totals/queue-counters (folded memset).
// ---------------------------------------------------------------------------
__global__ __launch_bounds__(256) void prep_kernel(
    const float* __restrict__ feat, __bf16* __restrict__ featbf,
    float* __restrict__ diag, float* __restrict__ rowsum,
    float* __restrict__ totals, int* __restrict__ qctr)
{
    // folded accumulator zeroing: 128 blocks x 256 threads = 32768 = B*D
    if (blockIdx.x < 128) {
        rowsum[blockIdx.x * 256 + threadIdx.x] = 0.0f;
        if (blockIdx.x == 0 && threadIdx.x < B_) totals[threadIdx.x] = 0.0f;
        if (blockIdx.x == 0 && threadIdx.x < 8) qctr[threadIdx.x] = 0;
    }

    const int w = threadIdx.x >> 6, l = threadIdx.x & 63;
    const int row = blockIdx.x * 4 + w;          // 0 .. 32767
    const float4* fp = (const float4*)(feat + (size_t)row * M_);
    float4 v0 = fp[l * 2];
    float4 v1 = fp[l * 2 + 1];
    bf16x8 h;
    h[0] = (__bf16)v0.x; h[1] = (__bf16)v0.y; h[2] = (__bf16)v0.z; h[3] = (__bf16)v0.w;
    h[4] = (__bf16)v1.x; h[5] = (__bf16)v1.y; h[6] = (__bf16)v1.z; h[7] = (__bf16)v1.w;
    *(bf16x8*)(featbf + (size_t)row * M_ + l * 8) = h;
    float s = v0.x*v0.x + v0.y*v0.y + v0.z*v0.z + v0.w*v0.w
            + v1.x*v1.x + v1.y*v1.y + v1.z*v1.z + v1.w*v1.w;
    #pragma unroll
    for (int off = 32; off; off >>= 1) s += __shfl_down(s, off);
    if (l == 0) diag[row] = s * (1.0f / (2.0f * M_));
}

// ---------------------------------------------------------------------------
// Kernel B: upper-triangular-tile Gram GEMM (bf16 MFMA 16x16x32), fused
// dcov -> pow epilogue. PERSISTENT-BLOCK version: grid = 768 = exactly
// 3 blocks/CU (the LDS cap), each block pulls tiles from a per-XCD-group
// atomic work queue (bid&7 partitions 768 blocks into 8 groups of 96; each
// group owns 4 batches x 36 tiles, batch-major -> same L2 locality as the
// old static swizzle). Removes the 1.5-generation quantization (1152 blocks
// at 768 residency ran gen-2 at a half-idle machine). Work-stealing is
// residency-assumption-free: a late block just finds its queue empty.
// K-loop: BK=32, depth-2 prefetch into 3 LDS buffers, raw s_barrier +
// counted s_waitcnt vmcnt(4), 2-way-free LDS swizzle, setprio around MFMA.
// ---------------------------------------------------------------------------
__global__ __launch_bounds__(256, 3) void gram_kernel(
    const __bf16* __restrict__ feat, const float* __restrict__ diag,
    float* __restrict__ out, float* __restrict__ rowsum,
    float* __restrict__ totals, int* __restrict__ qctr)
{
    // [stage%3][slot] ; slot = row*4 + swizzled-chunk, 16B per slot
    __shared__ __bf16 As[3][512 * 8];
    __shared__ __bf16 Bs[3][512 * 8];
    __shared__ int qsh;

    const int t = threadIdx.x;
    const int w = t >> 6, l = t & 63;
    const int quad = l >> 4, l15 = l & 15;
    const int wm = w >> 1, wn = w & 1;

    const int xcd = blockIdx.x & 7;          // heuristic XCD id (96 blocks/group)
    int* ctr = qctr + xcd;

    for (;;) {
        // -------- grab next tile from this group's queue --------
        if (t == 0) qsh = atomicAdd(ctr, 1);
        __syncthreads();
        const int q = qsh;                   // uniform across block
        if (q >= 144) return;                // 4 batches x 36 tiles done

        const int b = xcd + 8 * (q / 36);    // batch-major: L2 panel reuse
        const int rank = q % 36;
        int u = rank, ti = 0;
        while (u >= 8 - ti) { u -= 8 - ti; ti++; }
        const int tj = ti + u;
        const bool diagTile = (ti == tj);

        const __bf16* Ab = feat + (size_t)b * (D_ * M_) + (size_t)ti * 128 * M_;
        const __bf16* Bb = feat + (size_t)b * (D_ * M_) + (size_t)tj * 128 * M_;

        // Preload diag fragments: latency hides under the K-loop.
        const int gi0 = ti * 128 + wm * 64;
        const int gj0 = tj * 128 + wn * 64;
        const float* diagB = diag + b * D_;
        float di[4][4], dj[4];
        #pragma unroll
        for (int mi = 0; mi < 4; ++mi)
            #pragma unroll
            for (int r = 0; r < 4; ++r)
                di[mi][r] = diagB[gi0 + mi * 16 + quad * 4 + r];
        #pragma unroll
        for (int nj = 0; nj < 4; ++nj)
            dj[nj] = diagB[gj0 + nj * 16 + l15];

        f32x4 acc[4][4] = {};

        // stage s: load A/B rows [0,128) cols [s*32,s*32+32) into buffer sb.
        // LDS dest linear per wave (global_load_lds rule); bank swizzle is
        // applied on the per-lane GLOBAL source address (m173 pattern).
        auto stage = [&](int s, int sb) {
            const int koff = s * 32;
            #pragma unroll
            for (int it = 0; it < 2; ++it) {
                const int idx = it * 256 + t;          // slot 0..511
                const int row = idx >> 2;              // 0..127
                const int cg = (idx & 3) ^ ((row >> 1) & 3);  // swizzled chunk
                const __bf16* ga = Ab + row * M_ + koff + cg * 8;
                const __bf16* gb = Bb + row * M_ + koff + cg * 8;
                __builtin_amdgcn_global_load_lds(
                    (const __attribute__((address_space(1))) void*)ga,
                    (__attribute__((address_space(3))) void*)(&As[sb][(it * 256 + w * 64) * 8]),
                    16, 0, 0);
                __builtin_amdgcn_global_load_lds(
                    (const __attribute__((address_space(1))) void*)gb,
                    (__attribute__((address_space(3))) void*)(&Bs[sb][(it * 256 + w * 64) * 8]),
                    16, 0, 0);
            }
        };

        stage(0, 0);          // 4 loads/thread in flight
        stage(1, 1);          // 8 in flight
        int rb = 0, sn = 2;   // read buffer, next stage buffer
        for (int k0 = 0; k0 < 16; ++k0) {
            // Counted wait: own buffer-k0 loads (oldest 4) complete; the 4
            // prefetch loads for k0+1 stay in flight across the barrier.
            if (k0 < 15) asm volatile("s_waitcnt vmcnt(4)" ::: "memory");
            else         asm volatile("s_waitcnt vmcnt(0)" ::: "memory");
            __builtin_amdgcn_s_barrier();
            __builtin_amdgcn_sched_barrier(0);   // pin: nothing above barrier
            if (k0 + 2 < 16) stage(k0 + 2, sn);  // depth-2 prefetch

            bf16x8 af[4], bfr[4];
            #pragma unroll
            for (int mi = 0; mi < 4; ++mi) {
                const int row = wm * 64 + mi * 16 + l15;
                af[mi] = *(const bf16x8*)(&As[rb][(row * 4 + (quad ^ ((row >> 1) & 3))) * 8]);
            }
            #pragma unroll
            for (int nj = 0; nj < 4; ++nj) {
                const int row = wn * 64 + nj * 16 + l15;
                bfr[nj] = *(const bf16x8*)(&Bs[rb][(row * 4 + (quad ^ ((row >> 1) & 3))) * 8]);
            }
            __builtin_amdgcn_s_setprio(1);
            #pragma unroll
            for (int mi = 0; mi < 4; ++mi)
                #pragma unroll
                for (int nj = 0; nj < 4; ++nj)
                    acc[mi][nj] = __builtin_amdgcn_mfma_f32_16x16x32_bf16(
                        af[mi], bfr[nj], acc[mi][nj], 0, 0, 0);
            __builtin_amdgcn_s_setprio(0);
            rb = (rb == 2) ? 0 : rb + 1;
            sn = (sn == 2) ? 0 : sn + 1;
        }

        // ---------------- epilogue ----------------
        float* outB = out + (size_t)b * OUTROW;
        float rs[4][4] = {};
        float cs[4] = {};
        float wt = 0.f;
        const float invK = 1.0f / 512.0f;  // dcov = di + dj - dot/512

        #pragma unroll
        for (int mi = 0; mi < 4; ++mi) {
            #pragma unroll
            for (int nj = 0; nj < 4; ++nj) {
                const f32x4 a = acc[mi][nj];
                const int j = gj0 + nj * 16 + l15;
                #pragma unroll
                for (int r = 0; r < 4; ++r) {
                    const int i = gi0 + mi * 16 + quad * 4 + r;
                    float d = di[mi][r] + dj[nj] - a[r] * invK;
                    if (i == j) d = 0.0f;   // exact: ref has dcov(i,i) == 0
                    d = fmaxf(d, 0.0f);
                    const float p = __builtin_exp2f(ALPHA_ * __builtin_log2f(d + EPS_));
                    rs[mi][r] += p;
                    cs[nj] += p;
                    wt += p;
                    if (!diagTile || j >= i)
                        outB[(size_t)i * D_ - ((size_t)i * (i + 1)) / 2 + j] = p;
                }
            }
        }

        // row-sum contributions: reduce across l15 lanes
        #pragma unroll
        for (int mi = 0; mi < 4; ++mi) {
            #pragma unroll
            for (int r = 0; r < 4; ++r) {
                float v = rs[mi][r];
                v += __shfl_xor(v, 1); v += __shfl_xor(v, 2);
                v += __shfl_xor(v, 4); v += __shfl_xor(v, 8);
                if (l15 == 0)
                    unsafeAtomicAdd(&rowsum[b * D_ + gi0 + mi * 16 + quad * 4 + r], v);
            }
        }
        // col-sum contributions map to rowsum[j] by symmetry (off-diag only)
        if (!diagTile) {
            #pragma unroll
            for (int nj = 0; nj < 4; ++nj) {
                float v = cs[nj];
                v += __shfl_xor(v, 16); v += __shfl_xor(v, 32);
                if (quad == 0)
                    unsafeAtomicAdd(&rowsum[b * D_ + gj0 + nj * 16 + l15], v);
            }
        }
        // batch total (off-diag tiles counted twice: tile + mirror)
        float v = wt;
        #pragma unroll
        for (int off = 32; off; off >>= 1) v += __shfl_down(v, off);
        if (l == 0) unsafeAtomicAdd(&totals[b], diagTile ? v : 2.0f * v);

        // next tile: the qsh __syncthreads at loop top settles block state.
    }
}

// ---------------------------------------------------------------------------
// Kernel C: in-place double-centering, LINEAR float4 pass over the packed
// triangle (fully coalesced 16B/lane RMW, grid-stride, 2048 blocks).
// Row i recovered from flat index e via closed-form sqrt + integer fixup:
//   start(i) = i*(2D+1-i)/2 ;  i = floor((2D+1 - sqrt((2D+1)^2 - 8e)) / 2)
// ---------------------------------------------------------------------------
__global__ __launch_bounds__(256) void center_kernel(
    float* __restrict__ out, const float* __restrict__ rowsum,
    const float* __restrict__ totals)
{
    const int tot4 = OUTROW / 4;             // 131200 float4s per batch
    const float invD = 1.0f / (float)D_;
    const int gsz = gridDim.x * 256;

    for (int g = blockIdx.x * 256 + threadIdx.x; g < B_ * tot4; g += gsz) {
        const int b = g / tot4;              // magic-mul (constant divisor)
        const int e = (g - b * tot4) * 4;    // element index in packed triangle
        const float* rsB = rowsum + b * D_;
        const float tm = totals[b] * (1.0f / ((float)D_ * (float)D_));
        float* outB = out + (size_t)b * OUTROW;

        // row from flat index (D=1024: (2D+1)^2 = 2049^2 = 4198401)
        const float disc = 4198401.0f - 8.0f * (float)e;
        int i = (int)((2049.0f - __builtin_sqrtf(disc)) * 0.5f);
        if (i > 1023) i = 1023;
        if (i < 0) i = 0;
        // integer fixup for approx-sqrt boundary error
        while (i * (2049 - i) / 2 > e) --i;
        while ((i + 1) * (2049 - (i + 1)) / 2 <= e) ++i;

        float4 v = *(float4*)(outB + e);
        float r[4] = {v.x, v.y, v.z, v.w};
        int ii = i;
        int si = ii * (2049 - ii) / 2;            // start(ii)
        int sn = (ii + 1) * (2049 - ii - 1) / 2;  // start(ii+1)
        #pragma unroll
        for (int q = 0; q < 4; ++q) {
            const int eq = e + q;
            while (eq >= sn) {                    // row crossing (short rows)
                ++ii; si = sn;
                sn = (ii + 1) * (2049 - ii - 1) / 2;
            }
            const int j = eq - si + ii;
            r[q] = r[q] - (rsB[ii] + rsB[j]) * invD + tm;
        }
        v.x = r[0]; v.y = r[1]; v.z = r[2]; v.w = r[3];
        *(float4*)(outB + e) = v;
    }
}

// ---------------------------------------------------------------------------
extern "C" void kernel_launch(void* const* d_in, const int* in_sizes, int n_in,
                              void* d_out, int out_size, void* d_ws, size_t ws_size,
                              hipStream_t stream) {
    const float* feat = (const float*)d_in[0];
    float* out = (float*)d_out;

    char* ws = (char*)d_ws;
    __bf16* featbf = (__bf16*)ws;                            // 33,554,432 B
    float* diag    = (float*)(ws + 33554432);                //    131,072 B
    float* rowsum  = (float*)(ws + 33554432 + 131072);       //    131,072 B
    float* totals  = (float*)(ws + 33554432 + 262144);       //        128 B
    int*   qctr    = (int*)  (ws + 33554432 + 262144 + 128); //         32 B

    // rowsum/totals/qctr zeroing folded into prep_kernel (stream-ordered
    // before gram)
    prep_kernel<<<dim3((B_ * D_) / 4), dim3(256), 0, stream>>>(feat, featbf, diag,
                                                               rowsum, totals, qctr);
    gram_kernel<<<dim3(768), dim3(256), 0, stream>>>(featbf, diag, out, rowsum,
                                                     totals, qctr);
    center_kernel<<<dim3(2048), dim3(256), 0, stream>>>(out, rowsum, totals);
}